// Round 19
// baseline (70.185 us; speedup 1.0000x reference)
//
#include <hip/hip_runtime.h>
#include <math.h>

#define NN 262144
#define PP 64
#define QQ 64
#define TT 2048
#define JJ 512
#define BB 8
#define HH 64

__device__ __forceinline__ float lane_bcast(float v, int l) {
  return __int_as_float(__builtin_amdgcn_readlane(__float_as_int(v), l));
}

// ------- kernel 1: FUSED block-per-segment: ew(LDS) -> shuffle-free sums ----
// Phase 1: k_w's proven math on this segment's rows -> ew_lds (<=384 rows,
// 22 sigma above the binomial max). Phase 2: segS's shuffle-free loop; ew
// comes from uniform-address ds_read_b128 (broadcast, conflict-free), V as
// coalesced dwords; 16 VALU/row; tiny LDS epilogue. No ew global buffer,
// no seg_start buffer, no shuffles in phase 2.
__global__ __launch_bounds__(256) void k_fusedS(const float* __restrict__ Kmat,
                                                const int* __restrict__ idx,
                                                const float* __restrict__ S,
                                                const float* __restrict__ V,
                                                const int* __restrict__ seg_ids,
                                                float* __restrict__ M) {
  __shared__ __align__(16) float s_cols[BB * PP];     // [b][p]   2 KB
  __shared__ __align__(16) float ew_lds[384 * 8];     //         12 KB
  __shared__ __align__(16) float accred[4][8][64];    //          8 KB
  __shared__ float reds[4][8];
  __shared__ int bounds[2];
  int tid = threadIdx.x;
  int t = blockIdx.x;
  if (tid < 2) {
    int target = t + tid;
    int lo = 0, hi = NN;
    while (lo < hi) {
      int mid = (lo + hi) >> 1;
      if (seg_ids[mid] < target) lo = mid + 1; else hi = mid;
    }
    bounds[tid] = lo;
  }
  for (int i = tid; i < BB * PP; i += 256) {
    int p = i >> 3, b = i & 7;
    s_cols[b * PP + p] = S[p * JJ + idx[b]];
  }
  __syncthreads();
  int s = bounds[0], e = bounds[1];

  // ---- phase 1: ew for rows [s,e), 64 rows per pass, 4 lanes per row ----
  {
    int row_in = tid >> 2, sub = tid & 3;
#pragma unroll
    for (int pass = 0; pass < 6; ++pass) {
      int base = s + (pass << 6);
      if (base >= e) break;                 // block-uniform
      int row = base + row_in;
      if (row < e) {                        // uniform within the 4-lane group
        const float4* Kp = reinterpret_cast<const float4*>(Kmat + (size_t)row * PP + sub * 16);
        float4 kq[4];
#pragma unroll
        for (int j = 0; j < 4; ++j) kq[j] = Kp[j];
        float a8[8];
#pragma unroll
        for (int b = 0; b < 8; ++b) a8[b] = 0.f;
#pragma unroll
        for (int j4 = 0; j4 < 4; ++j4) {
          float4 kk = kq[j4];
#pragma unroll
          for (int b = 0; b < 8; ++b) {
            const float4 sv = *reinterpret_cast<const float4*>(&s_cols[b * PP + sub * 16 + j4 * 4]);
            a8[b] += kk.x * sv.x + kk.y * sv.y + kk.z * sv.z + kk.w * sv.w;
          }
        }
#pragma unroll
        for (int b = 0; b < 8; ++b) {
          a8[b] += __shfl_xor(a8[b], 1);
          a8[b] += __shfl_xor(a8[b], 2);
        }
        float ox = (sub == 0) ? a8[0] : (sub == 1) ? a8[2] : (sub == 2) ? a8[4] : a8[6];
        float oy = (sub == 0) ? a8[1] : (sub == 1) ? a8[3] : (sub == 2) ? a8[5] : a8[7];
        *reinterpret_cast<float2*>(&ew_lds[(row - s) * 8 + 2 * sub]) =
            make_float2(__expf(ox), __expf(oy));
      }
    }
  }
  __syncthreads();

  // ---- phase 2: shuffle-free accumulation, lane owns q = lane ----
  int lane = tid & 63, w = tid >> 6;
  int len = e - s;
  int chunk = (len + 3) >> 2;
  int b0 = s + w * chunk;
  int b1 = b0 + chunk; if (b1 > e) b1 = e; if (b1 < b0) b1 = b0;

  float acc[8], se[8];
#pragma unroll
  for (int b = 0; b < 8; ++b) { acc[b] = 0.f; se[b] = 0.f; }

  int r = b0;
  for (; r + 4 <= b1; r += 4) {
#pragma unroll
    for (int u = 0; u < 4; ++u) {
      int ro = r + u - s;
      float4 elo = *reinterpret_cast<const float4*>(&ew_lds[ro * 8]);      // uniform -> broadcast
      float4 ehi = *reinterpret_cast<const float4*>(&ew_lds[ro * 8 + 4]);
      float v = V[(size_t)(r + u) * QQ + lane];
      acc[0] += elo.x * v; acc[1] += elo.y * v; acc[2] += elo.z * v; acc[3] += elo.w * v;
      acc[4] += ehi.x * v; acc[5] += ehi.y * v; acc[6] += ehi.z * v; acc[7] += ehi.w * v;
      se[0] += elo.x; se[1] += elo.y; se[2] += elo.z; se[3] += elo.w;
      se[4] += ehi.x; se[5] += ehi.y; se[6] += ehi.z; se[7] += ehi.w;
    }
  }
  for (; r < b1; ++r) {
    int ro = r - s;
    float4 elo = *reinterpret_cast<const float4*>(&ew_lds[ro * 8]);
    float4 ehi = *reinterpret_cast<const float4*>(&ew_lds[ro * 8 + 4]);
    float v = V[(size_t)r * QQ + lane];
    acc[0] += elo.x * v; acc[1] += elo.y * v; acc[2] += elo.z * v; acc[3] += elo.w * v;
    acc[4] += ehi.x * v; acc[5] += ehi.y * v; acc[6] += ehi.z * v; acc[7] += ehi.w * v;
    se[0] += elo.x; se[1] += elo.y; se[2] += elo.z; se[3] += elo.w;
    se[4] += ehi.x; se[5] += ehi.y; se[6] += ehi.z; se[7] += ehi.w;
  }

  // ---- tiny epilogue: 8 LDS stores per lane + cross-wave combine ----
#pragma unroll
  for (int b = 0; b < 8; ++b) accred[w][b][lane] = acc[b];
  if (lane == 0) {
#pragma unroll
    for (int b = 0; b < 8; ++b) reds[w][b] = se[b];
  }
  __syncthreads();
  for (int o = tid; o < 512; o += 256) {
    int b = o >> 6, q = o & 63;
    float dd = reds[0][b] + reds[1][b] + reds[2][b] + reds[3][b];
    float inv = (dd > 0.f) ? 1.f / dd : 0.f;
    float sum = accred[0][b][q] + accred[1][b][q] + accred[2][b][q] + accred[3][b][q];
    M[(size_t)t * 512 + o] = sum * inv;   // M[t][b][q]
  }
}

// -------- kernel 2: GI[rho][g] = W_ih[g,:] . X[rho,:] + b_ih ----------------
__global__ __launch_bounds__(256) void k_gi(const float* __restrict__ M,
                                            const float* __restrict__ W_ih,
                                            const float* __restrict__ b_ih,
                                            float* __restrict__ GI) {
  __shared__ float Wt[64 * 193];
  int tid = threadIdx.x;
  for (int i = tid; i < 192 * 64; i += 256) {
    int g = i >> 6, k = i & 63;
    Wt[k * 193 + g] = W_ih[i];
  }
  __syncthreads();
  int lane = tid & 63, wv = tid >> 6;
  int row0 = blockIdx.x * 32 + wv * 8;
  float x[8];
#pragma unroll
  for (int rr = 0; rr < 8; ++rr) {
    int rho = row0 + rr;
    int b = rho >> 11, t = rho & 2047;
    x[rr] = M[((size_t)t * 8 + b) * 64 + lane];
  }
  float bi0 = b_ih[lane], bi1 = b_ih[64 + lane], bi2 = b_ih[128 + lane];
  float a0[8], a1[8], a2[8];
#pragma unroll
  for (int rr = 0; rr < 8; ++rr) { a0[rr] = bi0; a1[rr] = bi1; a2[rr] = bi2; }
#pragma unroll
  for (int k = 0; k < 64; ++k) {
    float w0 = Wt[k * 193 + lane];
    float w1 = Wt[k * 193 + 64 + lane];
    float w2 = Wt[k * 193 + 128 + lane];
#pragma unroll
    for (int rr = 0; rr < 8; ++rr) {
      float xk = lane_bcast(x[rr], k);
      a0[rr] += w0 * xk; a1[rr] += w1 * xk; a2[rr] += w2 * xk;
    }
  }
#pragma unroll
  for (int rr = 0; rr < 8; ++rr) {
    size_t rho = (size_t)row0 + rr;
    GI[rho * 192 + lane]       = a0[rr];
    GI[rho * 192 + 64 + lane]  = a1[rr];
    GI[rho * 192 + 128 + lane] = a2[rr];
  }
}

// -------- kernel 3: GRU, one t-row per wave, b128 W reads, padded LDS -------
__global__ __launch_bounds__(256) void k_gru(const float* __restrict__ GI,
                                             const float* __restrict__ W_hh,
                                             const float* __restrict__ b_hh,
                                             const float* __restrict__ w_out,
                                             const float* __restrict__ b_out,
                                             float* __restrict__ preds) {
  __shared__ __align__(16) float Wl[192 * 68];
  int tid = threadIdx.x;
  for (int i = tid; i < 192 * 16; i += 256) {
    int g = i >> 4, c = i & 15;
    *reinterpret_cast<float4*>(&Wl[g * 68 + c * 4]) =
        *reinterpret_cast<const float4*>(W_hh + g * 64 + c * 4);
  }
  __syncthreads();
  int lane = tid & 63, wv = tid >> 6;
  int t = blockIdx.x * 4 + wv;
  float bh0 = b_hh[lane], bh1 = b_hh[64 + lane], bh2 = b_hh[128 + lane];
  float wo = w_out[lane];
  float bo = b_out[0];
  const float* w0base = &Wl[lane * 68];
  const float* w1base = &Wl[(64 + lane) * 68];
  const float* w2base = &Wl[(128 + lane) * 68];

  float gr[8], gz[8], gn[8];
#pragma unroll
  for (int b = 0; b < 8; ++b) {
    size_t base = ((size_t)b * TT + t) * 192;
    gr[b] = GI[base + lane];
    gz[b] = GI[base + 64 + lane];
    gn[b] = GI[base + 128 + lane];
  }

  float h;
  {
    float r = 1.f / (1.f + __expf(-(gr[0] + bh0)));
    float z = 1.f / (1.f + __expf(-(gz[0] + bh1)));
    float nv = tanhf(gn[0] + r * bh2);
    h = (1.f - z) * nv;
    float pv = h * wo;
#pragma unroll
    for (int off = 32; off; off >>= 1) pv += __shfl_xor(pv, off);
    if (lane == 0) preds[t] = pv + bo;
  }
#pragma unroll
  for (int b = 1; b < 8; ++b) {
    float ar = bh0, az = bh1, an = bh2;
#pragma unroll
    for (int c = 0; c < 16; ++c) {
      const float4 w0 = *reinterpret_cast<const float4*>(w0base + c * 4);
      const float4 w1 = *reinterpret_cast<const float4*>(w1base + c * 4);
      const float4 w2 = *reinterpret_cast<const float4*>(w2base + c * 4);
      float a0 = lane_bcast(h, c * 4 + 0), a1 = lane_bcast(h, c * 4 + 1);
      float a2 = lane_bcast(h, c * 4 + 2), a3 = lane_bcast(h, c * 4 + 3);
      ar += w0.x * a0 + w0.y * a1 + w0.z * a2 + w0.w * a3;
      az += w1.x * a0 + w1.y * a1 + w1.z * a2 + w1.w * a3;
      an += w2.x * a0 + w2.y * a1 + w2.z * a2 + w2.w * a3;
    }
    float r = 1.f / (1.f + __expf(-(gr[b] + ar)));
    float z = 1.f / (1.f + __expf(-(gz[b] + az)));
    float nv = tanhf(gn[b] + r * an);
    h = (1.f - z) * nv + z * h;
    float pv = h * wo;
#pragma unroll
    for (int off = 32; off; off >>= 1) pv += __shfl_xor(pv, off);
    if (lane == 0) preds[(size_t)b * TT + t] = pv + bo;
  }
}

extern "C" void kernel_launch(void* const* d_in, const int* in_sizes, int n_in,
                              void* d_out, int out_size, void* d_ws, size_t ws_size,
                              hipStream_t stream) {
  const int*   idx     = (const int*)d_in[0];
  const int*   seg_ids = (const int*)d_in[1];
  const float* Kmat    = (const float*)d_in[2];
  const float* V       = (const float*)d_in[3];
  const float* S       = (const float*)d_in[4];
  const float* W_ih    = (const float*)d_in[5];
  const float* W_hh    = (const float*)d_in[6];
  const float* b_ih    = (const float*)d_in[7];
  const float* b_hh    = (const float*)d_in[8];
  const float* w_out   = (const float*)d_in[9];
  const float* b_out   = (const float*)d_in[10];
  float* out = (float*)d_out;

  char* ws = (char*)d_ws;
  float* M  = (float*)(ws + 0);          // T*8*64 f    4.2 MB
  float* GI = (float*)(ws + 4194304);    // 8*T*192 f  12.6 MB

  hipLaunchKernelGGL(k_fusedS, dim3(TT), dim3(256), 0, stream,
                     Kmat, idx, S, V, seg_ids, M);
  hipLaunchKernelGGL(k_gi, dim3(512), dim3(256), 0, stream, M, W_ih, b_ih, GI);
  hipLaunchKernelGGL(k_gru, dim3(512), dim3(256), 0, stream, GI, W_hh, b_hh, w_out, b_out, out);
}